// Round 1
// baseline (129.680 us; speedup 1.0000x reference)
//
#include <hip/hip_runtime.h>

// ContrastiveQueueLoss: V (2,256,128) f32, L (256,128) f32, queue (65536,128) f32
// loss = -(1/256) * sum_{m<512} ( pos[m] - log( Spos[j(m)] + Sq[m] ) )
//   pos[m] = 10 * dot(Vflat[m], L[m%256])
//   Spos[j] = sum_b exp(pos[j*256+b])
//   Sq[m]   = sum_q exp(10 * dot(Vflat[m], queue[q]))

typedef float  float4v __attribute__((ext_vector_type(4)));
typedef short  short8  __attribute__((ext_vector_type(8)));

__device__ __forceinline__ unsigned short f2bf(float f) {
    union { float f; unsigned u; } v; v.f = f;
    unsigned r = v.u + 0x7FFFu + ((v.u >> 16) & 1u);   // RNE (inputs are finite)
    return (unsigned short)(r >> 16);
}

// ---------------------------------------------------------------- prep ----
// 64 blocks x 256 threads. Zeros Sq (8 entries/block) and computes pos[512].
__global__ void prep_kernel(const float* __restrict__ V,
                            const float* __restrict__ L,
                            float* __restrict__ pos,
                            float* __restrict__ Sq) {
    const int blk  = blockIdx.x;
    const int tid  = threadIdx.x;
    if (tid < 8) Sq[blk * 8 + tid] = 0.0f;
    const int w    = tid >> 6;
    const int lane = tid & 63;
    #pragma unroll
    for (int i = 0; i < 2; ++i) {
        const int r = blk * 8 + w * 2 + i;      // row in [0,512)
        const int b = r & 255;
        const float2 v = *reinterpret_cast<const float2*>(V + r * 128 + lane * 2);
        const float2 l = *reinterpret_cast<const float2*>(L + b * 128 + lane * 2);
        float p = v.x * l.x + v.y * l.y;
        #pragma unroll
        for (int off = 32; off; off >>= 1) p += __shfl_xor(p, off);
        if (lane == 0) pos[r] = 10.0f * p;
    }
}

// ------------------------------------------------------------ gemm_exp ----
// Grid (512, 4), 256 threads (4 waves). Each block: 128(M) x 128(N) tile,
// K = 128 single-shot. fp32 -> bf16 conversion fused into LDS staging.
// LDS tiles use a 16B-chunk XOR swizzle: element (row, k) lives at
//   row*128 + (((k>>3) ^ (row & 15)) << 3) + (k & 7)
// -> frag ds_read_b128 is 2-way-conflict max (free), total LDS = 64 KB.
__global__ __launch_bounds__(256) void gemm_exp_kernel(
        const float* __restrict__ V,
        const float* __restrict__ Q,
        float* __restrict__ Sq) {
    __shared__ unsigned short As[128 * 128];
    __shared__ unsigned short Bs[128 * 128];

    const int tid = threadIdx.x;
    const int m0  = blockIdx.y * 128;
    const int n0  = blockIdx.x * 128;

    // ---- stage: 128x128 fp32 -> bf16 into swizzled LDS (A and B) ----
    #pragma unroll
    for (int i = 0; i < 16; ++i) {
        const int idx = i * 256 + tid;     // float4 index within the tile
        const int row = idx >> 5;          // 32 float4 per row of 128
        const int c4  = idx & 31;          // float4 column
        const float4 a = *reinterpret_cast<const float4*>(V + (m0 + row) * 128 + c4 * 4);
        const float4 b = *reinterpret_cast<const float4*>(Q + (n0 + row) * 128 + c4 * 4);
        const int chunk = ((c4 >> 1) ^ (row & 15));
        const int off   = row * 128 + (chunk << 3) + ((c4 & 1) << 2);
        const uint2 pa = make_uint2((unsigned)f2bf(a.x) | ((unsigned)f2bf(a.y) << 16),
                                    (unsigned)f2bf(a.z) | ((unsigned)f2bf(a.w) << 16));
        const uint2 pb = make_uint2((unsigned)f2bf(b.x) | ((unsigned)f2bf(b.y) << 16),
                                    (unsigned)f2bf(b.z) | ((unsigned)f2bf(b.w) << 16));
        *reinterpret_cast<uint2*>(&As[off]) = pa;
        *reinterpret_cast<uint2*>(&Bs[off]) = pb;
    }
    __syncthreads();

    const int w    = tid >> 6;
    const int lane = tid & 63;
    const int quad = lane >> 4;
    const int l16  = lane & 15;
    const int wrow = (w >> 1) * 64;
    const int wcol = (w & 1) * 64;

    float4v acc[4][4];
    #pragma unroll
    for (int mi = 0; mi < 4; ++mi)
        #pragma unroll
        for (int ni = 0; ni < 4; ++ni)
            acc[mi][ni] = (float4v){0.f, 0.f, 0.f, 0.f};

    #pragma unroll
    for (int kk = 0; kk < 4; ++kk) {
        const int kchunk = kk * 4 + quad;          // 16B chunk index along K
        short8 a[4], b[4];
        #pragma unroll
        for (int mi = 0; mi < 4; ++mi) {
            const int row = wrow + mi * 16 + l16;
            a[mi] = *reinterpret_cast<const short8*>(&As[row * 128 + ((kchunk ^ (row & 15)) << 3)]);
        }
        #pragma unroll
        for (int ni = 0; ni < 4; ++ni) {
            const int row = wcol + ni * 16 + l16;
            b[ni] = *reinterpret_cast<const short8*>(&Bs[row * 128 + ((kchunk ^ (row & 15)) << 3)]);
        }
        #pragma unroll
        for (int mi = 0; mi < 4; ++mi)
            #pragma unroll
            for (int ni = 0; ni < 4; ++ni)
                acc[mi][ni] = __builtin_amdgcn_mfma_f32_16x16x32_bf16(a[mi], b[ni], acc[mi][ni], 0, 0, 0);
    }

    // All waves done reading LDS tiles before we alias As as rowsum storage.
    __syncthreads();
    float* rowsum = reinterpret_cast<float*>(As);   // [2][128] floats

    // ---- exp + per-row partial sums ----
    // D layout (16x16x32): col = lane&15, row = quad*4 + reg.
    #pragma unroll
    for (int mi = 0; mi < 4; ++mi) {
        float rs[4] = {0.f, 0.f, 0.f, 0.f};
        #pragma unroll
        for (int ni = 0; ni < 4; ++ni)
            #pragma unroll
            for (int r = 0; r < 4; ++r)
                rs[r] += __expf(10.0f * acc[mi][ni][r]);
        #pragma unroll
        for (int r = 0; r < 4; ++r) {
            float vsum = rs[r];
            vsum += __shfl_xor(vsum, 1);
            vsum += __shfl_xor(vsum, 2);
            vsum += __shfl_xor(vsum, 4);
            vsum += __shfl_xor(vsum, 8);
            if (l16 == 0)
                rowsum[(w & 1) * 128 + wrow + mi * 16 + quad * 4 + r] = vsum;
        }
    }
    __syncthreads();

    if (tid < 128)
        atomicAdd(&Sq[m0 + tid], rowsum[tid] + rowsum[128 + tid]);
}

// ------------------------------------------------------------ finalize ----
// 1 block x 512 threads.
__global__ void finalize_kernel(const float* __restrict__ pos,
                                const float* __restrict__ Sq,
                                float* __restrict__ out) {
    __shared__ float wsum[8];
    __shared__ float Sp[2];
    const int tid  = threadIdx.x;     // 0..511
    const int w    = tid >> 6;
    const int lane = tid & 63;

    const float p = pos[tid];
    float e = __expf(p);
    #pragma unroll
    for (int off = 32; off; off >>= 1) e += __shfl_xor(e, off);
    if (lane == 0) wsum[w] = e;
    __syncthreads();
    if (tid == 0) {
        Sp[0] = wsum[0] + wsum[1] + wsum[2] + wsum[3];
        Sp[1] = wsum[4] + wsum[5] + wsum[6] + wsum[7];
    }
    __syncthreads();

    const int j = tid >> 8;
    float contrib = p - __logf(Sp[j] + Sq[tid]);
    #pragma unroll
    for (int off = 32; off; off >>= 1) contrib += __shfl_xor(contrib, off);
    if (lane == 0) wsum[w] = contrib;
    __syncthreads();
    if (tid == 0) {
        float tot = 0.f;
        #pragma unroll
        for (int i = 0; i < 8; ++i) tot += wsum[i];
        out[0] = -tot / 256.0f;
    }
}

// -------------------------------------------------------------- launch ----
extern "C" void kernel_launch(void* const* d_in, const int* in_sizes, int n_in,
                              void* d_out, int out_size, void* d_ws, size_t ws_size,
                              hipStream_t stream) {
    const float* V     = (const float*)d_in[0];   // (2,256,128)
    const float* L     = (const float*)d_in[1];   // (256,128)
    const float* queue = (const float*)d_in[2];   // (65536,128)
    float* out = (float*)d_out;

    float* pos = (float*)d_ws;        // 512 floats
    float* Sq  = pos + 512;           // 512 floats

    prep_kernel<<<64, 256, 0, stream>>>(V, L, pos, Sq);
    dim3 grid(512, 4);
    gemm_exp_kernel<<<grid, 256, 0, stream>>>(V, queue, Sq);
    finalize_kernel<<<1, 512, 0, stream>>>(pos, Sq, out);
}

// Round 2
// 115.403 us; speedup vs baseline: 1.1237x; 1.1237x over previous
//
#include <hip/hip_runtime.h>

// ContrastiveQueueLoss: V (2,256,128) f32, L (256,128) f32, queue (65536,128) f32
// loss = -(1/256) * sum_{m<512} ( pos[m] - log( Spos[j(m)] + Sq[m] ) )

typedef float  float4v __attribute__((ext_vector_type(4)));
typedef short  short8  __attribute__((ext_vector_type(8)));

#define AS1 __attribute__((address_space(1)))
#define AS3 __attribute__((address_space(3)))

__device__ __forceinline__ unsigned short f2bf(float f) {
    union { float f; unsigned u; } v; v.f = f;
    unsigned r = v.u + 0x7FFFu + ((v.u >> 16) & 1u);   // RNE (inputs finite)
    return (unsigned short)(r >> 16);
}

// ======================================================= fast path =========

// 2048 blocks x 256. Converts queue->bf16 (qbf) and V->bf16 (abf); blocks
// 64..127 also compute pos[512] and zero Sq[512].
__global__ __launch_bounds__(256) void convert_prep_kernel(
        const float* __restrict__ V, const float* __restrict__ L,
        const float* __restrict__ Qf,
        unsigned short* __restrict__ qbf, unsigned short* __restrict__ abf,
        float* __restrict__ pos, float* __restrict__ Sq) {
    const int tid = threadIdx.x;
    const int gt  = blockIdx.x * 256 + tid;
    const float4* q4 = (const float4*)Qf;
    uint2* qo = (uint2*)qbf;
    #pragma unroll
    for (int i = 0; i < 4; ++i) {                 // 8.39M floats total
        const int g = i * 524288 + gt;
        const float4 q = q4[g];
        uint2 p;
        p.x = (unsigned)f2bf(q.x) | ((unsigned)f2bf(q.y) << 16);
        p.y = (unsigned)f2bf(q.z) | ((unsigned)f2bf(q.w) << 16);
        qo[g] = p;
    }
    if (blockIdx.x < 64) {                        // V: 16384 float4s
        const float4 v = ((const float4*)V)[gt];
        uint2 p;
        p.x = (unsigned)f2bf(v.x) | ((unsigned)f2bf(v.y) << 16);
        p.y = (unsigned)f2bf(v.z) | ((unsigned)f2bf(v.w) << 16);
        ((uint2*)abf)[gt] = p;
    } else if (blockIdx.x < 128) {                // pos + Sq zero
        const int blk  = blockIdx.x - 64;
        if (tid < 8) Sq[blk * 8 + tid] = 0.0f;
        const int w    = tid >> 6;
        const int lane = tid & 63;
        #pragma unroll
        for (int i = 0; i < 2; ++i) {
            const int r = blk * 8 + w * 2 + i;    // row in [0,512)
            const int b = r & 255;
            const float2 v = *reinterpret_cast<const float2*>(V + r * 128 + lane * 2);
            const float2 l = *reinterpret_cast<const float2*>(L + b * 128 + lane * 2);
            float p = v.x * l.x + v.y * l.y;
            #pragma unroll
            for (int off = 32; off; off >>= 1) p += __shfl_xor(p, off);
            if (lane == 0) pos[r] = 10.0f * p;
        }
    }
}

// 256 blocks x 256 threads (1 block/CU, 97 KB LDS).
// bid: mt = bid>>7 (M-tile of 256 rows), ng = bid&127 (512 queue rows).
// A (256x128 bf16) staged once via global_load_lds with source-side XOR
// swizzle; 8 B-tiles (64x128) double-buffered with raw s_barrier + manual
// s_waitcnt vmcnt(4) so the next tile's DMA stays in flight across barriers.
// Element (row,kchunk c) lives at LDS chunk row*16 + (c ^ (row&15)).
__global__ __launch_bounds__(256, 1) void gemm_exp_kernel(
        const unsigned short* __restrict__ abf,
        const unsigned short* __restrict__ qbf,
        float* __restrict__ Sq) {
    __shared__ unsigned short As[256 * 128];      // 64 KB
    __shared__ unsigned short Bs[2][64 * 128];    // 2 x 16 KB
    __shared__ float rowsum[256];

    const int tid  = threadIdx.x;
    const int bid  = blockIdx.x;
    const int mt   = bid >> 7;
    const int ng   = bid & 127;
    const int m0   = mt * 256;
    const int nb   = ng * 512;

    const int w    = tid >> 6;
    const int lane = tid & 63;
    const int quad = lane >> 4;
    const int l16  = lane & 15;
    const int wrow = w * 64;                      // wave owns 64 M-rows

    // ---- A stage: 4096 16B chunks, 16 rounds x 256 lanes ----
    #pragma unroll
    for (int r = 0; r < 16; ++r) {
        const int slot = r * 256 + w * 64 + lane;
        const int row  = slot >> 4;
        const int cc   = slot & 15;
        const int c    = cc ^ (row & 15);
        const unsigned short* src = abf + (m0 + row) * 128 + c * 8;
        __builtin_amdgcn_global_load_lds((AS1 void*)src,
            (AS3 void*)&As[(r * 256 + w * 64) * 8], 16, 0, 0);
    }

    auto issueB = [&](int t) {
        unsigned short* buf = &Bs[t & 1][0];
        const unsigned short* base = qbf + (nb + t * 64) * 128;
        #pragma unroll
        for (int r = 0; r < 4; ++r) {
            const int slot = r * 256 + w * 64 + lane;
            const int row  = slot >> 4;
            const int cc   = slot & 15;
            const int c    = cc ^ (row & 15);
            __builtin_amdgcn_global_load_lds((AS1 void*)(base + row * 128 + c * 8),
                (AS3 void*)&buf[(r * 256 + w * 64) * 8], 16, 0, 0);
        }
    };
    issueB(0);
    issueB(1);

    float rs[4][4];
    #pragma unroll
    for (int mi = 0; mi < 4; ++mi)
        #pragma unroll
        for (int r = 0; r < 4; ++r) rs[mi][r] = 0.0f;

    #pragma unroll
    for (int t = 0; t < 8; ++t) {
        if (t < 7) __builtin_amdgcn_s_waitcnt(0x0F74);   // vmcnt(4): next tile in flight
        else       __builtin_amdgcn_s_waitcnt(0x0F70);   // vmcnt(0)
        __builtin_amdgcn_s_barrier();
        const unsigned short* buf = &Bs[t & 1][0];

        float4v acc[4][4];
        #pragma unroll
        for (int mi = 0; mi < 4; ++mi)
            #pragma unroll
            for (int ni = 0; ni < 4; ++ni)
                acc[mi][ni] = (float4v){0.f, 0.f, 0.f, 0.f};

        #pragma unroll
        for (int kk = 0; kk < 4; ++kk) {
            const int c = kk * 4 + quad;
            short8 a[4], b[4];
            #pragma unroll
            for (int mi = 0; mi < 4; ++mi) {
                const int row = wrow + mi * 16 + l16;
                a[mi] = *(const short8*)&As[row * 128 + ((c ^ (row & 15)) << 3)];
            }
            #pragma unroll
            for (int ni = 0; ni < 4; ++ni) {
                const int row = ni * 16 + l16;
                b[ni] = *(const short8*)&buf[row * 128 + ((c ^ (row & 15)) << 3)];
            }
            #pragma unroll
            for (int mi = 0; mi < 4; ++mi)
                #pragma unroll
                for (int ni = 0; ni < 4; ++ni)
                    acc[mi][ni] = __builtin_amdgcn_mfma_f32_16x16x32_bf16(a[mi], b[ni], acc[mi][ni], 0, 0, 0);
        }

        // exp(10*x) = 2^(x * 10/ln2); accumulate row sums in registers
        #pragma unroll
        for (int mi = 0; mi < 4; ++mi)
            #pragma unroll
            for (int ni = 0; ni < 4; ++ni)
                #pragma unroll
                for (int r = 0; r < 4; ++r)
                    rs[mi][r] += exp2f(acc[mi][ni][r] * 14.426950408889634f);

        if (t + 2 < 8) {
            __builtin_amdgcn_s_barrier();   // everyone done reading Bs[t&1]
            issueB(t + 2);                  // overwrite it with tile t+2
        }
    }

    // ---- epilogue: reduce over 16 columns (l16), one atomic per row ----
    #pragma unroll
    for (int mi = 0; mi < 4; ++mi)
        #pragma unroll
        for (int r = 0; r < 4; ++r) {
            float v = rs[mi][r];
            v += __shfl_xor(v, 1);
            v += __shfl_xor(v, 2);
            v += __shfl_xor(v, 4);
            v += __shfl_xor(v, 8);
            if (l16 == 0) rowsum[wrow + mi * 16 + quad * 4 + r] = v;
        }
    __syncthreads();
    atomicAdd(&Sq[m0 + tid], rowsum[tid]);
}

// ======================================================= fallback path ====

__global__ void prep_kernel(const float* __restrict__ V,
                            const float* __restrict__ L,
                            float* __restrict__ pos,
                            float* __restrict__ Sq) {
    const int blk  = blockIdx.x;
    const int tid  = threadIdx.x;
    if (tid < 8) Sq[blk * 8 + tid] = 0.0f;
    const int w    = tid >> 6;
    const int lane = tid & 63;
    #pragma unroll
    for (int i = 0; i < 2; ++i) {
        const int r = blk * 8 + w * 2 + i;
        const int b = r & 255;
        const float2 v = *reinterpret_cast<const float2*>(V + r * 128 + lane * 2);
        const float2 l = *reinterpret_cast<const float2*>(L + b * 128 + lane * 2);
        float p = v.x * l.x + v.y * l.y;
        #pragma unroll
        for (int off = 32; off; off >>= 1) p += __shfl_xor(p, off);
        if (lane == 0) pos[r] = 10.0f * p;
    }
}

__global__ __launch_bounds__(256) void gemm_exp_fallback(
        const float* __restrict__ V,
        const float* __restrict__ Q,
        float* __restrict__ Sq) {
    __shared__ unsigned short As[128 * 128];
    __shared__ unsigned short Bs[128 * 128];
    const int tid = threadIdx.x;
    const int m0  = blockIdx.y * 128;
    const int n0  = blockIdx.x * 128;
    #pragma unroll
    for (int i = 0; i < 16; ++i) {
        const int idx = i * 256 + tid;
        const int row = idx >> 5;
        const int c4  = idx & 31;
        const float4 a = *reinterpret_cast<const float4*>(V + (m0 + row) * 128 + c4 * 4);
        const float4 b = *reinterpret_cast<const float4*>(Q + (n0 + row) * 128 + c4 * 4);
        const int chunk = ((c4 >> 1) ^ (row & 15));
        const int off   = row * 128 + (chunk << 3) + ((c4 & 1) << 2);
        const uint2 pa = make_uint2((unsigned)f2bf(a.x) | ((unsigned)f2bf(a.y) << 16),
                                    (unsigned)f2bf(a.z) | ((unsigned)f2bf(a.w) << 16));
        const uint2 pb = make_uint2((unsigned)f2bf(b.x) | ((unsigned)f2bf(b.y) << 16),
                                    (unsigned)f2bf(b.z) | ((unsigned)f2bf(b.w) << 16));
        *reinterpret_cast<uint2*>(&As[off]) = pa;
        *reinterpret_cast<uint2*>(&Bs[off]) = pb;
    }
    __syncthreads();
    const int w    = tid >> 6;
    const int lane = tid & 63;
    const int quad = lane >> 4;
    const int l16  = lane & 15;
    const int wrow = (w >> 1) * 64;
    const int wcol = (w & 1) * 64;
    float4v acc[4][4];
    #pragma unroll
    for (int mi = 0; mi < 4; ++mi)
        #pragma unroll
        for (int ni = 0; ni < 4; ++ni)
            acc[mi][ni] = (float4v){0.f, 0.f, 0.f, 0.f};
    #pragma unroll
    for (int kk = 0; kk < 4; ++kk) {
        const int kchunk = kk * 4 + quad;
        short8 a[4], b[4];
        #pragma unroll
        for (int mi = 0; mi < 4; ++mi) {
            const int row = wrow + mi * 16 + l16;
            a[mi] = *reinterpret_cast<const short8*>(&As[row * 128 + ((kchunk ^ (row & 15)) << 3)]);
        }
        #pragma unroll
        for (int ni = 0; ni < 4; ++ni) {
            const int row = wcol + ni * 16 + l16;
            b[ni] = *reinterpret_cast<const short8*>(&Bs[row * 128 + ((kchunk ^ (row & 15)) << 3)]);
        }
        #pragma unroll
        for (int mi = 0; mi < 4; ++mi)
            #pragma unroll
            for (int ni = 0; ni < 4; ++ni)
                acc[mi][ni] = __builtin_amdgcn_mfma_f32_16x16x32_bf16(a[mi], b[ni], acc[mi][ni], 0, 0, 0);
    }
    __syncthreads();
    float* rowsum = reinterpret_cast<float*>(As);
    #pragma unroll
    for (int mi = 0; mi < 4; ++mi) {
        float rsv[4] = {0.f, 0.f, 0.f, 0.f};
        #pragma unroll
        for (int ni = 0; ni < 4; ++ni)
            #pragma unroll
            for (int r = 0; r < 4; ++r)
                rsv[r] += __expf(10.0f * acc[mi][ni][r]);
        #pragma unroll
        for (int r = 0; r < 4; ++r) {
            float vsum = rsv[r];
            vsum += __shfl_xor(vsum, 1);
            vsum += __shfl_xor(vsum, 2);
            vsum += __shfl_xor(vsum, 4);
            vsum += __shfl_xor(vsum, 8);
            if (l16 == 0)
                rowsum[(w & 1) * 128 + wrow + mi * 16 + quad * 4 + r] = vsum;
        }
    }
    __syncthreads();
    if (tid < 128)
        atomicAdd(&Sq[m0 + tid], rowsum[tid] + rowsum[128 + tid]);
}

// ======================================================= finalize =========

__global__ void finalize_kernel(const float* __restrict__ pos,
                                const float* __restrict__ Sq,
                                float* __restrict__ out) {
    __shared__ float wsum[8];
    __shared__ float Sp[2];
    const int tid  = threadIdx.x;
    const int w    = tid >> 6;
    const int lane = tid & 63;
    const float p = pos[tid];
    float e = __expf(p);
    #pragma unroll
    for (int off = 32; off; off >>= 1) e += __shfl_xor(e, off);
    if (lane == 0) wsum[w] = e;
    __syncthreads();
    if (tid == 0) {
        Sp[0] = wsum[0] + wsum[1] + wsum[2] + wsum[3];
        Sp[1] = wsum[4] + wsum[5] + wsum[6] + wsum[7];
    }
    __syncthreads();
    const int j = tid >> 8;
    float contrib = p - __logf(Sp[j] + Sq[tid]);
    #pragma unroll
    for (int off = 32; off; off >>= 1) contrib += __shfl_xor(contrib, off);
    if (lane == 0) wsum[w] = contrib;
    __syncthreads();
    if (tid == 0) {
        float tot = 0.f;
        #pragma unroll
        for (int i = 0; i < 8; ++i) tot += wsum[i];
        out[0] = -tot / 256.0f;
    }
}

// ======================================================= launch ===========

extern "C" void kernel_launch(void* const* d_in, const int* in_sizes, int n_in,
                              void* d_out, int out_size, void* d_ws, size_t ws_size,
                              hipStream_t stream) {
    const float* V     = (const float*)d_in[0];   // (2,256,128)
    const float* L     = (const float*)d_in[1];   // (256,128)
    const float* queue = (const float*)d_in[2];   // (65536,128)
    float* out = (float*)d_out;

    const size_t need = (size_t)65536 * 128 * 2 + (size_t)512 * 128 * 2 + 1024 * 4;
    if (ws_size >= need) {
        unsigned short* qbf = (unsigned short*)d_ws;
        unsigned short* abf = qbf + (size_t)65536 * 128;
        float* pos = (float*)(abf + 512 * 128);
        float* Sq  = pos + 512;
        convert_prep_kernel<<<2048, 256, 0, stream>>>(V, L, queue, qbf, abf, pos, Sq);
        gemm_exp_kernel<<<256, 256, 0, stream>>>(abf, qbf, Sq);
        finalize_kernel<<<1, 512, 0, stream>>>(pos, Sq, out);
    } else {
        float* pos = (float*)d_ws;
        float* Sq  = pos + 512;
        prep_kernel<<<64, 256, 0, stream>>>(V, L, pos, Sq);
        dim3 grid(512, 4);
        gemm_exp_fallback<<<grid, 256, 0, stream>>>(V, queue, Sq);
        finalize_kernel<<<1, 512, 0, stream>>>(pos, Sq, out);
    }
}

// Round 3
// 106.844 us; speedup vs baseline: 1.2137x; 1.0801x over previous
//
#include <hip/hip_runtime.h>

// ContrastiveQueueLoss: V (2,256,128) f32, L (256,128) f32, queue (65536,128) f32
// loss = -(1/256) * sum_{m<512} ( pos[m] - log( Spos[j(m)] + Sq[m] ) )

typedef float  float4v __attribute__((ext_vector_type(4)));
typedef short  short8  __attribute__((ext_vector_type(8)));

#define AS1 __attribute__((address_space(1)))
#define AS3 __attribute__((address_space(3)))

__device__ __forceinline__ unsigned short f2bf(float f) {
    union { float f; unsigned u; } v; v.f = f;
    unsigned r = v.u + 0x7FFFu + ((v.u >> 16) & 1u);   // RNE (inputs finite)
    return (unsigned short)(r >> 16);
}

// ======================================================= fast path =========

// 2048 blocks x 256. Converts queue->bf16 (qbf) and V->bf16 (abf); blocks
// 64..127 also compute pos[512] and zero Sq[512].
__global__ __launch_bounds__(256) void convert_prep_kernel(
        const float* __restrict__ V, const float* __restrict__ L,
        const float* __restrict__ Qf,
        unsigned short* __restrict__ qbf, unsigned short* __restrict__ abf,
        float* __restrict__ pos, float* __restrict__ Sq) {
    const int tid = threadIdx.x;
    const int gt  = blockIdx.x * 256 + tid;
    const float4* q4 = (const float4*)Qf;
    uint2* qo = (uint2*)qbf;
    #pragma unroll
    for (int i = 0; i < 4; ++i) {                 // 8.39M floats total
        const int g = i * 524288 + gt;
        const float4 q = q4[g];
        uint2 p;
        p.x = (unsigned)f2bf(q.x) | ((unsigned)f2bf(q.y) << 16);
        p.y = (unsigned)f2bf(q.z) | ((unsigned)f2bf(q.w) << 16);
        qo[g] = p;
    }
    if (blockIdx.x < 64) {                        // V: 16384 float4s
        const float4 v = ((const float4*)V)[gt];
        uint2 p;
        p.x = (unsigned)f2bf(v.x) | ((unsigned)f2bf(v.y) << 16);
        p.y = (unsigned)f2bf(v.z) | ((unsigned)f2bf(v.w) << 16);
        ((uint2*)abf)[gt] = p;
    } else if (blockIdx.x < 128) {                // pos + Sq zero
        const int blk  = blockIdx.x - 64;
        if (tid < 8) Sq[blk * 8 + tid] = 0.0f;
        const int w    = tid >> 6;
        const int lane = tid & 63;
        #pragma unroll
        for (int i = 0; i < 2; ++i) {
            const int r = blk * 8 + w * 2 + i;    // row in [0,512)
            const int b = r & 255;
            const float2 v = *reinterpret_cast<const float2*>(V + r * 128 + lane * 2);
            const float2 l = *reinterpret_cast<const float2*>(L + b * 128 + lane * 2);
            float p = v.x * l.x + v.y * l.y;
            #pragma unroll
            for (int off = 32; off; off >>= 1) p += __shfl_xor(p, off);
            if (lane == 0) pos[r] = 10.0f * p;
        }
    }
}

// 512 blocks x 256 threads. mt = bid>>8 (256 M rows), ng = bid&255 (256 queue
// rows = 4 tiles of 64). Each wave keeps its 64x128 A-slice in REGISTERS
// (16 short8 = 64 VGPR); LDS holds only double-buffered 64x128 B tiles
// (2x16KB, XOR-swizzled) streamed via global_load_lds, with raw s_barrier +
// manual s_waitcnt vmcnt(4) so the next tile's DMA stays in flight.
// Element (row, 16B-chunk c) lives at chunk row*16 + (c ^ (row&15)).
__global__ __launch_bounds__(256, 2) void gemm_exp_kernel(
        const unsigned short* __restrict__ abf,
        const unsigned short* __restrict__ qbf,
        float* __restrict__ Sq) {
    __shared__ unsigned short Bs[2][64 * 128];    // 32 KB
    __shared__ float rowsum[256];

    const int tid  = threadIdx.x;
    const int bid  = blockIdx.x;
    const int mt   = bid >> 8;                    // 0..1 (mt pairs share XCD)
    const int ng   = bid & 255;
    const int m0   = mt * 256;
    const int nb   = ng * 256;                    // queue row base

    const int w    = tid >> 6;
    const int lane = tid & 63;
    const int quad = lane >> 4;
    const int l16  = lane & 15;
    const int wrow = w * 64;                      // wave owns 64 M rows

    // ---- A: 64x128 bf16 per wave, straight into registers ----
    short8 a[4][4];
    #pragma unroll
    for (int mi = 0; mi < 4; ++mi)
        #pragma unroll
        for (int kk = 0; kk < 4; ++kk)
            a[mi][kk] = *(const short8*)&abf[(m0 + wrow + mi * 16 + l16) * 128
                                             + (kk * 4 + quad) * 8];

    auto issueB = [&](int t) {
        unsigned short* buf = &Bs[t & 1][0];
        const unsigned short* base = qbf + (nb + t * 64) * 128;
        #pragma unroll
        for (int r = 0; r < 4; ++r) {
            const int slot = r * 256 + w * 64 + lane;
            const int row  = slot >> 4;
            const int c    = (slot & 15) ^ (row & 15);
            __builtin_amdgcn_global_load_lds((AS1 void*)(base + row * 128 + c * 8),
                (AS3 void*)&buf[(r * 256 + w * 64) * 8], 16, 0, 0);
        }
    };
    issueB(0);
    issueB(1);

    float rs[4][4];
    #pragma unroll
    for (int mi = 0; mi < 4; ++mi)
        #pragma unroll
        for (int r = 0; r < 4; ++r) rs[mi][r] = 0.0f;

    #pragma unroll 1
    for (int t = 0; t < 4; ++t) {
        if (t < 3) __builtin_amdgcn_s_waitcnt(0x0F74);   // vmcnt(4)
        else       __builtin_amdgcn_s_waitcnt(0x0F70);   // vmcnt(0)
        __builtin_amdgcn_s_barrier();
        const unsigned short* buf = &Bs[t & 1][0];

        float4v acc[4][4];
        #pragma unroll
        for (int mi = 0; mi < 4; ++mi)
            #pragma unroll
            for (int ni = 0; ni < 4; ++ni)
                acc[mi][ni] = (float4v){0.f, 0.f, 0.f, 0.f};

        #pragma unroll
        for (int kk = 0; kk < 4; ++kk) {
            const int c = kk * 4 + quad;
            short8 b[4];
            #pragma unroll
            for (int ni = 0; ni < 4; ++ni) {
                const int row = ni * 16 + l16;
                b[ni] = *(const short8*)&buf[row * 128 + ((c ^ (row & 15)) << 3)];
            }
            #pragma unroll
            for (int mi = 0; mi < 4; ++mi)
                #pragma unroll
                for (int ni = 0; ni < 4; ++ni)
                    acc[mi][ni] = __builtin_amdgcn_mfma_f32_16x16x32_bf16(
                        a[mi][kk], b[ni], acc[mi][ni], 0, 0, 0);
        }

        // exp(10*x) = 2^(x * 10/ln2); fold into register row sums
        #pragma unroll
        for (int mi = 0; mi < 4; ++mi)
            #pragma unroll
            for (int ni = 0; ni < 4; ++ni)
                #pragma unroll
                for (int r = 0; r < 4; ++r)
                    rs[mi][r] += exp2f(acc[mi][ni][r] * 14.426950408889634f);

        if (t < 2) {
            __builtin_amdgcn_s_barrier();   // all waves done reading Bs[t&1]
            issueB(t + 2);
        }
    }

    // ---- epilogue: reduce over 16 columns, one atomic per row ----
    #pragma unroll
    for (int mi = 0; mi < 4; ++mi)
        #pragma unroll
        for (int r = 0; r < 4; ++r) {
            float v = rs[mi][r];
            v += __shfl_xor(v, 1);
            v += __shfl_xor(v, 2);
            v += __shfl_xor(v, 4);
            v += __shfl_xor(v, 8);
            if (l16 == 0) rowsum[wrow + mi * 16 + quad * 4 + r] = v;
        }
    __syncthreads();
    atomicAdd(&Sq[m0 + tid], rowsum[tid]);
}

// ======================================================= fallback path ====

__global__ void prep_kernel(const float* __restrict__ V,
                            const float* __restrict__ L,
                            float* __restrict__ pos,
                            float* __restrict__ Sq) {
    const int blk  = blockIdx.x;
    const int tid  = threadIdx.x;
    if (tid < 8) Sq[blk * 8 + tid] = 0.0f;
    const int w    = tid >> 6;
    const int lane = tid & 63;
    #pragma unroll
    for (int i = 0; i < 2; ++i) {
        const int r = blk * 8 + w * 2 + i;
        const int b = r & 255;
        const float2 v = *reinterpret_cast<const float2*>(V + r * 128 + lane * 2);
        const float2 l = *reinterpret_cast<const float2*>(L + b * 128 + lane * 2);
        float p = v.x * l.x + v.y * l.y;
        #pragma unroll
        for (int off = 32; off; off >>= 1) p += __shfl_xor(p, off);
        if (lane == 0) pos[r] = 10.0f * p;
    }
}

__global__ __launch_bounds__(256) void gemm_exp_fallback(
        const float* __restrict__ V,
        const float* __restrict__ Q,
        float* __restrict__ Sq) {
    __shared__ unsigned short As[128 * 128];
    __shared__ unsigned short Bs[128 * 128];
    const int tid = threadIdx.x;
    const int m0  = blockIdx.y * 128;
    const int n0  = blockIdx.x * 128;
    #pragma unroll
    for (int i = 0; i < 16; ++i) {
        const int idx = i * 256 + tid;
        const int row = idx >> 5;
        const int c4  = idx & 31;
        const float4 a = *reinterpret_cast<const float4*>(V + (m0 + row) * 128 + c4 * 4);
        const float4 b = *reinterpret_cast<const float4*>(Q + (n0 + row) * 128 + c4 * 4);
        const int chunk = ((c4 >> 1) ^ (row & 15));
        const int off   = row * 128 + (chunk << 3) + ((c4 & 1) << 2);
        const uint2 pa = make_uint2((unsigned)f2bf(a.x) | ((unsigned)f2bf(a.y) << 16),
                                    (unsigned)f2bf(a.z) | ((unsigned)f2bf(a.w) << 16));
        const uint2 pb = make_uint2((unsigned)f2bf(b.x) | ((unsigned)f2bf(b.y) << 16),
                                    (unsigned)f2bf(b.z) | ((unsigned)f2bf(b.w) << 16));
        *reinterpret_cast<uint2*>(&As[off]) = pa;
        *reinterpret_cast<uint2*>(&Bs[off]) = pb;
    }
    __syncthreads();
    const int w    = tid >> 6;
    const int lane = tid & 63;
    const int quad = lane >> 4;
    const int l16  = lane & 15;
    const int wrow = (w >> 1) * 64;
    const int wcol = (w & 1) * 64;
    float4v acc[4][4];
    #pragma unroll
    for (int mi = 0; mi < 4; ++mi)
        #pragma unroll
        for (int ni = 0; ni < 4; ++ni)
            acc[mi][ni] = (float4v){0.f, 0.f, 0.f, 0.f};
    #pragma unroll
    for (int kk = 0; kk < 4; ++kk) {
        const int kchunk = kk * 4 + quad;
        short8 a[4], b[4];
        #pragma unroll
        for (int mi = 0; mi < 4; ++mi) {
            const int row = wrow + mi * 16 + l16;
            a[mi] = *reinterpret_cast<const short8*>(&As[row * 128 + ((kchunk ^ (row & 15)) << 3)]);
        }
        #pragma unroll
        for (int ni = 0; ni < 4; ++ni) {
            const int row = wcol + ni * 16 + l16;
            b[ni] = *reinterpret_cast<const short8*>(&Bs[row * 128 + ((kchunk ^ (row & 15)) << 3)]);
        }
        #pragma unroll
        for (int mi = 0; mi < 4; ++mi)
            #pragma unroll
            for (int ni = 0; ni < 4; ++ni)
                acc[mi][ni] = __builtin_amdgcn_mfma_f32_16x16x32_bf16(a[mi], b[ni], acc[mi][ni], 0, 0, 0);
    }
    __syncthreads();
    float* rowsum = reinterpret_cast<float*>(As);
    #pragma unroll
    for (int mi = 0; mi < 4; ++mi) {
        float rsv[4] = {0.f, 0.f, 0.f, 0.f};
        #pragma unroll
        for (int ni = 0; ni < 4; ++ni)
            #pragma unroll
            for (int r = 0; r < 4; ++r)
                rsv[r] += __expf(10.0f * acc[mi][ni][r]);
        #pragma unroll
        for (int r = 0; r < 4; ++r) {
            float vsum = rsv[r];
            vsum += __shfl_xor(vsum, 1);
            vsum += __shfl_xor(vsum, 2);
            vsum += __shfl_xor(vsum, 4);
            vsum += __shfl_xor(vsum, 8);
            if (l16 == 0)
                rowsum[(w & 1) * 128 + wrow + mi * 16 + quad * 4 + r] = vsum;
        }
    }
    __syncthreads();
    if (tid < 128)
        atomicAdd(&Sq[m0 + tid], rowsum[tid] + rowsum[128 + tid]);
}

// ======================================================= finalize =========

__global__ void finalize_kernel(const float* __restrict__ pos,
                                const float* __restrict__ Sq,
                                float* __restrict__ out) {
    __shared__ float wsum[8];
    __shared__ float Sp[2];
    const int tid  = threadIdx.x;
    const int w    = tid >> 6;
    const int lane = tid & 63;
    const float p = pos[tid];
    float e = __expf(p);
    #pragma unroll
    for (int off = 32; off; off >>= 1) e += __shfl_xor(e, off);
    if (lane == 0) wsum[w] = e;
    __syncthreads();
    if (tid == 0) {
        Sp[0] = wsum[0] + wsum[1] + wsum[2] + wsum[3];
        Sp[1] = wsum[4] + wsum[5] + wsum[6] + wsum[7];
    }
    __syncthreads();
    const int j = tid >> 8;
    float contrib = p - __logf(Sp[j] + Sq[tid]);
    #pragma unroll
    for (int off = 32; off; off >>= 1) contrib += __shfl_xor(contrib, off);
    if (lane == 0) wsum[w] = contrib;
    __syncthreads();
    if (tid == 0) {
        float tot = 0.f;
        #pragma unroll
        for (int i = 0; i < 8; ++i) tot += wsum[i];
        out[0] = -tot / 256.0f;
    }
}

// ======================================================= launch ===========

extern "C" void kernel_launch(void* const* d_in, const int* in_sizes, int n_in,
                              void* d_out, int out_size, void* d_ws, size_t ws_size,
                              hipStream_t stream) {
    const float* V     = (const float*)d_in[0];   // (2,256,128)
    const float* L     = (const float*)d_in[1];   // (256,128)
    const float* queue = (const float*)d_in[2];   // (65536,128)
    float* out = (float*)d_out;

    const size_t need = (size_t)65536 * 128 * 2 + (size_t)512 * 128 * 2 + 1024 * 4;
    if (ws_size >= need) {
        unsigned short* qbf = (unsigned short*)d_ws;
        unsigned short* abf = qbf + (size_t)65536 * 128;
        float* pos = (float*)(abf + 512 * 128);
        float* Sq  = pos + 512;
        convert_prep_kernel<<<2048, 256, 0, stream>>>(V, L, queue, qbf, abf, pos, Sq);
        gemm_exp_kernel<<<512, 256, 0, stream>>>(abf, qbf, Sq);
        finalize_kernel<<<1, 512, 0, stream>>>(pos, Sq, out);
    } else {
        float* pos = (float*)d_ws;
        float* Sq  = pos + 512;
        prep_kernel<<<64, 256, 0, stream>>>(V, L, pos, Sq);
        dim3 grid(512, 4);
        gemm_exp_fallback<<<grid, 256, 0, stream>>>(V, queue, Sq);
        finalize_kernel<<<1, 512, 0, stream>>>(pos, Sq, out);
    }
}